// Round 3
// baseline (393.176 us; speedup 1.0000x reference)
//
#include <hip/hip_runtime.h>

// B=2, H=16, S=2048, DK=DV=64; out flat = [B,H,S,DV] flat (raw reshape).
#define S_LEN 2048
#define DHEAD 64
#define BHEADS 32
#define NTILES 32                       // key tiles of 64
#define HEAD_ELEMS (S_LEN * DHEAD)
#define TENS_ELEMS (BHEADS * HEAD_ELEMS)
#define TILE_HALVES 4096                // 8 KB per (bh,tile) fragment block

typedef _Float16 half8_t __attribute__((ext_vector_type(8)));
typedef _Float16 half4_t __attribute__((ext_vector_type(4)));
typedef _Float16 half2_t __attribute__((ext_vector_type(2)));
typedef float float4_t __attribute__((ext_vector_type(4)));

// 1/sqrt(64) * log2(e), folded into K so scores land in exp2 domain
#define SC_LOG2E 0.18033688011112042f

// Fragment-linear layouts (16 B per lane per fragment):
//  Kf[bh][t][f=mt*2+kh][lane] : K[t*64 + mt*16 + (lane&15)][kh*32 + (lane>>4)*8 + j] * SC
//  Vf[bh][t][fv=vt*2+c][lane][j] : V[t*64 + c*32 + (j>>2)*16 + (lane>>4)*4 + (j&3)]
//                                   [vt*16 + (lane&15)]
// Key fact (R9): Vf's k-ordering equals the k-ordering of a P^T B-operand
// built by concatenating QK sub-tile outputs 2c (regs 0-3) and 2c+1 (regs
// 4-7), so PV can use mfma_f32_16x16x32_f16 directly — half the PV MFMAs.

// ---------------- prepass: build fragment-ordered K/VT ----------------
__global__ __launch_bounds__(256) void prep_kernel(const float* __restrict__ K,
                                                   const float* __restrict__ V,
                                                   _Float16* __restrict__ Kf,
                                                   _Float16* __restrict__ Vf) {
    __shared__ _Float16 tile[64][72];   // V tile [s][v], padded
    const int bh = blockIdx.x >> 5;
    const int t = blockIdx.x & 31;
    const int tid = threadIdx.x;

    const float* Ksrc = K + (bh * S_LEN + t * 64) * DHEAD;
    const float4* vs = (const float4*)(V + (bh * S_LEN + t * 64) * DHEAD);
#pragma unroll
    for (int it = 0; it < 4; ++it) {
        int i = it * 256 + tid;                 // 1024 float4 = 64x64 floats
        float4 vv = vs[i];
        int r = i >> 4, c4 = (i & 15) * 4;
        half4_t hv = {(_Float16)vv.x, (_Float16)vv.y, (_Float16)vv.z, (_Float16)vv.w};
        *(half4_t*)&tile[r][c4] = hv;
    }

    // K fragments: pure permutation of the fp32 tile, no LDS needed
    _Float16* kd = Kf + (bh * NTILES + t) * TILE_HALVES;
#pragma unroll
    for (int it = 0; it < 2; ++it) {
        int c = it * 256 + tid;                 // 512 chunks of 16 B
        int f = c >> 6, lane = c & 63;
        int row = (f >> 1) * 16 + (lane & 15);
        int d0 = (f & 1) * 32 + (lane >> 4) * 8;
        const float4* s = (const float4*)(Ksrc + row * DHEAD + d0);
        float4 a = s[0], b = s[1];
        half8_t h = {(_Float16)(a.x * SC_LOG2E), (_Float16)(a.y * SC_LOG2E),
                     (_Float16)(a.z * SC_LOG2E), (_Float16)(a.w * SC_LOG2E),
                     (_Float16)(b.x * SC_LOG2E), (_Float16)(b.y * SC_LOG2E),
                     (_Float16)(b.z * SC_LOG2E), (_Float16)(b.w * SC_LOG2E)};
        *(half8_t*)(kd + c * 8) = h;
    }
    __syncthreads();

    // VT fragments: transpose gather from LDS
    _Float16* vd = Vf + (bh * NTILES + t) * TILE_HALVES;
#pragma unroll
    for (int it = 0; it < 2; ++it) {
        int c = it * 256 + tid;
        int fv = c >> 6, lane = c & 63;
        int vt = fv >> 1, ktp = fv & 1;
        int v = vt * 16 + (lane & 15);
        int g = lane >> 4;
        half8_t h;
#pragma unroll
        for (int j = 0; j < 8; ++j) {
            int key = ktp * 32 + (j >> 2) * 16 + g * 4 + (j & 3);
            h[j] = tile[key][v];
        }
        *(half8_t*)(vd + c * 8) = h;
    }
}

// ---------------- attention: split-K x4, nq=4, 4 waves/SIMD ----------------
// Block = 4 waves = ONE q-group (64 queries) x 4 k-splits (8 tiles each).
// R12: occupancy was grid-limited, not resource-limited. Old decomposition
// (2 q-groups x 2 splits) gave 2048 waves total = 2 waves/SIMD; at VGPR=108
// the HW allows 16 waves/CU. Split-K x4 doubles waves to 4096 = 4 waves/SIMD
// with ZERO extra KV L2 traffic (waves read disjoint tiles). R10's version of
// this idea failed because it shrank blocks and capped VGPRs into spill;
// here block stays 256 thr and per-wave structure is untouched.
// R11 post-mortem: manual register prefetch was neutral (compiler already
// software-pipelines the barrier-free loop with counted vmcnt) -> reverted.
// Combine: 3-barrier tree {1,3}->{0,2} then 2->0, reusing 2 LDS buffers
// (34.8 KB -> 4 blocks/CU fits 160 KB LDS).
// XCD swizzle (R8, kept): head = blockIdx % 32 => KV L2-resident per XCD.
// nq=4 + K=32 PV (R9): double independent MFMA chains, halve PV MFMA count.

__global__ __launch_bounds__(256, 4) void attn_kernel(
    const float* __restrict__ Qf,
    const _Float16* __restrict__ Kf,
    const _Float16* __restrict__ Vf,
    float* __restrict__ out) {
    __shared__ float red[2][68][64];    // [buf][64 o-floats + 4 lsum][lane]

    const int tid = threadIdx.x;
    const int wid = tid >> 6;
    const int lane = tid & 63;
    const int ln15 = lane & 15;
    const int g = lane >> 4;

    const int bh = blockIdx.x & 31;          // head-major: head h -> XCD h%8
    const int qidx = blockIdx.x >> 5;        // 32 q-blocks per head (64 q each)
    const int ks = wid;                      // k-split quarter (0..3)
    const int q0 = qidx * 64;
    const int t0 = ks * 8;                   // this wave's 8 key tiles

    // ---- Q fragments (B-operand of 16x16x32), direct global fp32 -> f16 ----
    const float* Qg = Qf + (bh * S_LEN + q0) * DHEAD;
    half8_t qf[4][2];
#pragma unroll
    for (int nq = 0; nq < 4; ++nq)
#pragma unroll
        for (int kh = 0; kh < 2; ++kh) {
            const float4* qs = (const float4*)(Qg + (nq * 16 + ln15) * DHEAD + kh * 32 + g * 8);
            float4 a = qs[0], b = qs[1];
            qf[nq][kh] = (half8_t){(_Float16)a.x, (_Float16)a.y, (_Float16)a.z, (_Float16)a.w,
                                   (_Float16)b.x, (_Float16)b.y, (_Float16)b.z, (_Float16)b.w};
        }

    const _Float16* kb = Kf + bh * (NTILES * TILE_HALVES) + t0 * TILE_HALVES;
    const _Float16* vb = Vf + bh * (NTILES * TILE_HALVES) + t0 * TILE_HALVES;
    const int lo = lane * 8;                  // lane offset in halves

    float lsum[4] = {0.f, 0.f, 0.f, 0.f};
    float4_t o[4][4];
#pragma unroll
    for (int nq = 0; nq < 4; ++nq)
#pragma unroll
        for (int vt = 0; vt < 4; ++vt) o[nq][vt] = (float4_t){0.f, 0.f, 0.f, 0.f};

#pragma unroll 2
    for (int t = 0; t < 8; ++t) {
        const int base = t * TILE_HALVES;
        half8_t kf[8], vf[8];
#pragma unroll
        for (int f = 0; f < 8; ++f) kf[f] = *(const half8_t*)(kb + base + f * 512 + lo);
#pragma unroll
        for (int f = 0; f < 8; ++f) vf[f] = *(const half8_t*)(vb + base + f * 512 + lo);

        // two 32-key chunks; QK -> exp2 -> PV (K=32) per chunk
#pragma unroll
        for (int c = 0; c < 2; ++c) {
            half8_t pb[4];
#pragma unroll
            for (int h = 0; h < 2; ++h) {
                const int mt = 2 * c + h;
                half8_t a0 = kf[mt * 2];
                half8_t a1 = kf[mt * 2 + 1];
#pragma unroll
                for (int nq = 0; nq < 4; ++nq) {
                    float4_t c0 = (float4_t){0.f, 0.f, 0.f, 0.f};
                    c0 = __builtin_amdgcn_mfma_f32_16x16x32_f16(a0, qf[nq][0], c0, 0, 0, 0);
                    c0 = __builtin_amdgcn_mfma_f32_16x16x32_f16(a1, qf[nq][1], c0, 0, 0, 0);
                    float p0 = __builtin_amdgcn_exp2f(c0[0]);
                    float p1 = __builtin_amdgcn_exp2f(c0[1]);
                    float p2 = __builtin_amdgcn_exp2f(c0[2]);
                    float p3 = __builtin_amdgcn_exp2f(c0[3]);
                    lsum[nq] += (p0 + p1) + (p2 + p3);
                    half2_t plo = __builtin_bit_cast(half2_t, __builtin_amdgcn_cvt_pkrtz(p0, p1));
                    half2_t phi = __builtin_bit_cast(half2_t, __builtin_amdgcn_cvt_pkrtz(p2, p3));
                    pb[nq][h * 4 + 0] = plo[0];
                    pb[nq][h * 4 + 1] = plo[1];
                    pb[nq][h * 4 + 2] = phi[0];
                    pb[nq][h * 4 + 3] = phi[1];
                }
            }
            // ---- O^T += V^T . P^T over this 32-key chunk (K=32 MFMA) ----
#pragma unroll
            for (int vt = 0; vt < 4; ++vt) {
                half8_t va = vf[vt * 2 + c];
#pragma unroll
                for (int nq = 0; nq < 4; ++nq)
                    o[nq][vt] = __builtin_amdgcn_mfma_f32_16x16x32_f16(va, pb[nq], o[nq][vt], 0, 0, 0);
            }
        }
    }

    // ---- cross-lane l reduction (per wave, over its key quarter) ----
#pragma unroll
    for (int nq = 0; nq < 4; ++nq) {
        float l = lsum[nq];
        l += __shfl_xor(l, 16, 64);
        l += __shfl_xor(l, 32, 64);
        lsum[nq] = l;                       // replicated across g-groups
    }

    // ---- split-K x4 combine: tree {1,3}->{0,2}, then 2->0 ----
    const int buf = ks >> 1;
    if (ks & 1) {                           // waves 1,3 publish
#pragma unroll
        for (int nq = 0; nq < 4; ++nq)
#pragma unroll
            for (int vt = 0; vt < 4; ++vt)
#pragma unroll
                for (int r = 0; r < 4; ++r)
                    red[buf][nq * 16 + vt * 4 + r][lane] = o[nq][vt][r];
#pragma unroll
        for (int nq = 0; nq < 4; ++nq) red[buf][64 + nq][lane] = lsum[nq];
    }
    __syncthreads();
    if (!(ks & 1)) {                        // waves 0,2 accumulate
#pragma unroll
        for (int nq = 0; nq < 4; ++nq) {
            lsum[nq] += red[buf][64 + nq][lane];
#pragma unroll
            for (int vt = 0; vt < 4; ++vt)
#pragma unroll
                for (int r = 0; r < 4; ++r)
                    o[nq][vt][r] += red[buf][nq * 16 + vt * 4 + r][lane];
        }
    }
    __syncthreads();
    if (ks == 2) {                          // wave 2 publishes its 2-way sum
#pragma unroll
        for (int nq = 0; nq < 4; ++nq)
#pragma unroll
            for (int vt = 0; vt < 4; ++vt)
#pragma unroll
                for (int r = 0; r < 4; ++r)
                    red[0][nq * 16 + vt * 4 + r][lane] = o[nq][vt][r];
#pragma unroll
        for (int nq = 0; nq < 4; ++nq) red[0][64 + nq][lane] = lsum[nq];
    }
    __syncthreads();
    if (ks == 0) {                          // wave 0 finalizes + stores
#pragma unroll
        for (int nq = 0; nq < 4; ++nq) {
            float lt = lsum[nq] + red[0][64 + nq][lane];
            float inv_l = 1.0f / lt;
            int qg_global = q0 + nq * 16 + ln15;
            float* og = out + (bh * S_LEN + qg_global) * DHEAD;
#pragma unroll
            for (int vt = 0; vt < 4; ++vt) {
                float4_t vals;
#pragma unroll
                for (int r = 0; r < 4; ++r)
                    vals[r] = (o[nq][vt][r] + red[0][nq * 16 + vt * 4 + r][lane]) * inv_l;
                *(float4_t*)(og + vt * 16 + g * 4) = vals;
            }
        }
    }
}

// ---------------- launch ----------------

extern "C" void kernel_launch(void* const* d_in, const int* in_sizes, int n_in,
                              void* d_out, int out_size, void* d_ws, size_t ws_size,
                              hipStream_t stream) {
    const float* Kin = (const float*)d_in[0];
    const float* Qin = (const float*)d_in[1];
    const float* Vin = (const float*)d_in[2];
    float* out = (float*)d_out;

    _Float16* Kf = (_Float16*)d_ws;                 // 8 MB
    _Float16* Vf = Kf + TENS_ELEMS;                 // 8 MB

    prep_kernel<<<BHEADS * NTILES, 256, 0, stream>>>(Kin, Vin, Kf, Vf);
    attn_kernel<<<BHEADS * 32, 256, 0, stream>>>(Qin, Kf, Vf, out);
}

// Round 4
// 133.498 us; speedup vs baseline: 2.9452x; 2.9452x over previous
//
#include <hip/hip_runtime.h>

// B=2, H=16, S=2048, DK=DV=64; out flat = [B,H,S,DV] flat (raw reshape).
#define S_LEN 2048
#define DHEAD 64
#define BHEADS 32
#define NTILES 32                       // key tiles of 64
#define HEAD_ELEMS (S_LEN * DHEAD)
#define TENS_ELEMS (BHEADS * HEAD_ELEMS)
#define TILE_HALVES 4096                // 8 KB per (bh,tile) fragment block

typedef _Float16 half8_t __attribute__((ext_vector_type(8)));
typedef _Float16 half4_t __attribute__((ext_vector_type(4)));
typedef _Float16 half2_t __attribute__((ext_vector_type(2)));
typedef float float4_t __attribute__((ext_vector_type(4)));

// 1/sqrt(64) * log2(e), folded into K so scores land in exp2 domain
#define SC_LOG2E 0.18033688011112042f

// Fragment-linear layouts (16 B per lane per fragment):
//  Kf[bh][t][f=mt*2+kh][lane] : K[t*64 + mt*16 + (lane&15)][kh*32 + (lane>>4)*8 + j] * SC
//  Vf[bh][t][fv=vt*2+c][lane][j] : V[t*64 + c*32 + (j>>2)*16 + (lane>>4)*4 + (j&3)]
//                                   [vt*16 + (lane&15)]
// Key fact (R9): Vf's k-ordering equals the k-ordering of a P^T B-operand
// built by concatenating QK sub-tile outputs 2c (regs 0-3) and 2c+1 (regs
// 4-7), so PV can use mfma_f32_16x16x32_f16 directly — half the PV MFMAs.

// ---------------- prepass: build fragment-ordered K/VT ----------------
__global__ __launch_bounds__(256) void prep_kernel(const float* __restrict__ K,
                                                   const float* __restrict__ V,
                                                   _Float16* __restrict__ Kf,
                                                   _Float16* __restrict__ Vf) {
    __shared__ _Float16 tile[64][72];   // V tile [s][v], padded
    const int bh = blockIdx.x >> 5;
    const int t = blockIdx.x & 31;
    const int tid = threadIdx.x;

    const float* Ksrc = K + (bh * S_LEN + t * 64) * DHEAD;
    const float4* vs = (const float4*)(V + (bh * S_LEN + t * 64) * DHEAD);
#pragma unroll
    for (int it = 0; it < 4; ++it) {
        int i = it * 256 + tid;                 // 1024 float4 = 64x64 floats
        float4 vv = vs[i];
        int r = i >> 4, c4 = (i & 15) * 4;
        half4_t hv = {(_Float16)vv.x, (_Float16)vv.y, (_Float16)vv.z, (_Float16)vv.w};
        *(half4_t*)&tile[r][c4] = hv;
    }

    // K fragments: pure permutation of the fp32 tile, no LDS needed
    _Float16* kd = Kf + (bh * NTILES + t) * TILE_HALVES;
#pragma unroll
    for (int it = 0; it < 2; ++it) {
        int c = it * 256 + tid;                 // 512 chunks of 16 B
        int f = c >> 6, lane = c & 63;
        int row = (f >> 1) * 16 + (lane & 15);
        int d0 = (f & 1) * 32 + (lane >> 4) * 8;
        const float4* s = (const float4*)(Ksrc + row * DHEAD + d0);
        float4 a = s[0], b = s[1];
        half8_t h = {(_Float16)(a.x * SC_LOG2E), (_Float16)(a.y * SC_LOG2E),
                     (_Float16)(a.z * SC_LOG2E), (_Float16)(a.w * SC_LOG2E),
                     (_Float16)(b.x * SC_LOG2E), (_Float16)(b.y * SC_LOG2E),
                     (_Float16)(b.z * SC_LOG2E), (_Float16)(b.w * SC_LOG2E)};
        *(half8_t*)(kd + c * 8) = h;
    }
    __syncthreads();

    // VT fragments: transpose gather from LDS
    _Float16* vd = Vf + (bh * NTILES + t) * TILE_HALVES;
#pragma unroll
    for (int it = 0; it < 2; ++it) {
        int c = it * 256 + tid;
        int fv = c >> 6, lane = c & 63;
        int vt = fv >> 1, ktp = fv & 1;
        int v = vt * 16 + (lane & 15);
        int g = lane >> 4;
        half8_t h;
#pragma unroll
        for (int j = 0; j < 8; ++j) {
            int key = ktp * 32 + (j >> 2) * 16 + g * 4 + (j & 3);
            h[j] = tile[key][v];
        }
        *(half8_t*)(vd + c * 8) = h;
    }
}

// ---------------- attention: nq=2, split-K x2, 4 waves/SIMD ----------------
// R13: occupancy must come WITH a halved register footprint, not a cap.
// R10/R12 post-mortem: launch_bounds(.,4) = 128-unified-reg cap; at nq=4 the
// o[4][4] accumulator alone is 64 AGPRs -> 64 arch VGPRs left for a ~110-reg
// live set -> huge spill (VGPR_Count=64 + 1.4GB scratch, twice). The nq=4
// structure fits only the 256-reg / 2-wave budget -> occupancy ceiling.
// This version: nq=2 (32 q/wave): o[2][4]=32 AGPR, qf 16, PER-CHUNK K/V frag
// loads (16+16 live vs 64), pb 8 -> ~110 unified, fits the 128 cap with slack.
// Block = 4 waves = 2 q-subgroups (32 q) x 2 k-splits (16 tiles).
// Grid = 32 heads x 32 q-blocks (64 q each) = 1024 blocks, 4096 waves
// = 4 waves/SIMD (2x the old 2048-wave shapes). exp2/MFMA totals unchanged
// (half per wave x 2x waves). KV L2 reads double to 512 MB (~18 TB/s at
// target time, well under 34.5 TB/s L2 ceiling); KV stays L2-resident/XCD.
// LDS 17.4 KB -> 4 blocks/CU. XCD swizzle (R8) and K=32 PV (R9) kept.

__global__ __launch_bounds__(256, 4) void attn_kernel(
    const float* __restrict__ Qf,
    const _Float16* __restrict__ Kf,
    const _Float16* __restrict__ Vf,
    float* __restrict__ out) {
    __shared__ float red[2][34][64];    // [qsub][32 o-floats + 2 lsum][lane]

    const int tid = threadIdx.x;
    const int wid = tid >> 6;
    const int lane = tid & 63;
    const int ln15 = lane & 15;
    const int g = lane >> 4;

    const int bh = blockIdx.x & 31;          // head-major: head h -> XCD h%8
    const int qidx = blockIdx.x >> 5;        // 32 q-blocks per head (64 q each)
    const int qsub = wid >> 1;               // q-subgroup within block (32 q)
    const int ks = wid & 1;                  // k-split half
    const int q0 = qidx * 64 + qsub * 32;
    const int t0 = ks * 16;                  // this wave's 16 key tiles

    // ---- Q fragments (B-operand of 16x16x32), direct global fp32 -> f16 ----
    const float* Qg = Qf + (bh * S_LEN + q0) * DHEAD;
    half8_t qf[2][2];
#pragma unroll
    for (int nq = 0; nq < 2; ++nq)
#pragma unroll
        for (int kh = 0; kh < 2; ++kh) {
            const float4* qs = (const float4*)(Qg + (nq * 16 + ln15) * DHEAD + kh * 32 + g * 8);
            float4 a = qs[0], b = qs[1];
            qf[nq][kh] = (half8_t){(_Float16)a.x, (_Float16)a.y, (_Float16)a.z, (_Float16)a.w,
                                   (_Float16)b.x, (_Float16)b.y, (_Float16)b.z, (_Float16)b.w};
        }

    const _Float16* kb = Kf + bh * (NTILES * TILE_HALVES) + t0 * TILE_HALVES;
    const _Float16* vb = Vf + bh * (NTILES * TILE_HALVES) + t0 * TILE_HALVES;
    const int lo = lane * 8;                  // lane offset in halves

    float lsum[2] = {0.f, 0.f};
    float4_t o[2][4];
#pragma unroll
    for (int nq = 0; nq < 2; ++nq)
#pragma unroll
        for (int vt = 0; vt < 4; ++vt) o[nq][vt] = (float4_t){0.f, 0.f, 0.f, 0.f};

#pragma unroll 2
    for (int t = 0; t < 16; ++t) {
        const int base = t * TILE_HALVES;

        // two 32-key chunks; per-chunk frag loads keep live set small
#pragma unroll
        for (int c = 0; c < 2; ++c) {
            half8_t kA[4], vA[4];
            // K frags for this chunk: f = 4c .. 4c+3 (contiguous)
#pragma unroll
            for (int i = 0; i < 4; ++i)
                kA[i] = *(const half8_t*)(kb + base + (4 * c + i) * 512 + lo);
            // V frags for this chunk: fv = vt*2 + c
#pragma unroll
            for (int vt = 0; vt < 4; ++vt)
                vA[vt] = *(const half8_t*)(vb + base + (vt * 2 + c) * 512 + lo);

            half8_t pb[2];
#pragma unroll
            for (int h = 0; h < 2; ++h) {
                half8_t a0 = kA[h * 2];
                half8_t a1 = kA[h * 2 + 1];
#pragma unroll
                for (int nq = 0; nq < 2; ++nq) {
                    float4_t c0 = (float4_t){0.f, 0.f, 0.f, 0.f};
                    c0 = __builtin_amdgcn_mfma_f32_16x16x32_f16(a0, qf[nq][0], c0, 0, 0, 0);
                    c0 = __builtin_amdgcn_mfma_f32_16x16x32_f16(a1, qf[nq][1], c0, 0, 0, 0);
                    float p0 = __builtin_amdgcn_exp2f(c0[0]);
                    float p1 = __builtin_amdgcn_exp2f(c0[1]);
                    float p2 = __builtin_amdgcn_exp2f(c0[2]);
                    float p3 = __builtin_amdgcn_exp2f(c0[3]);
                    lsum[nq] += (p0 + p1) + (p2 + p3);
                    half2_t plo = __builtin_bit_cast(half2_t, __builtin_amdgcn_cvt_pkrtz(p0, p1));
                    half2_t phi = __builtin_bit_cast(half2_t, __builtin_amdgcn_cvt_pkrtz(p2, p3));
                    pb[nq][h * 4 + 0] = plo[0];
                    pb[nq][h * 4 + 1] = plo[1];
                    pb[nq][h * 4 + 2] = phi[0];
                    pb[nq][h * 4 + 3] = phi[1];
                }
            }
            // ---- O^T += V^T . P^T over this 32-key chunk (K=32 MFMA) ----
#pragma unroll
            for (int vt = 0; vt < 4; ++vt) {
                half8_t va = vA[vt];
#pragma unroll
                for (int nq = 0; nq < 2; ++nq)
                    o[nq][vt] = __builtin_amdgcn_mfma_f32_16x16x32_f16(va, pb[nq], o[nq][vt], 0, 0, 0);
            }
        }
    }

    // ---- cross-lane l reduction (per wave, over its key half) ----
#pragma unroll
    for (int nq = 0; nq < 2; ++nq) {
        float l = lsum[nq];
        l += __shfl_xor(l, 16, 64);
        l += __shfl_xor(l, 32, 64);
        lsum[nq] = l;                       // replicated across g-groups
    }

    // ---- split-K combine via LDS (conflict-free column layout) ----
    if (ks == 1) {
#pragma unroll
        for (int nq = 0; nq < 2; ++nq)
#pragma unroll
            for (int vt = 0; vt < 4; ++vt)
#pragma unroll
                for (int r = 0; r < 4; ++r)
                    red[qsub][nq * 16 + vt * 4 + r][lane] = o[nq][vt][r];
#pragma unroll
        for (int nq = 0; nq < 2; ++nq) red[qsub][32 + nq][lane] = lsum[nq];
    }
    __syncthreads();
    if (ks == 0) {
#pragma unroll
        for (int nq = 0; nq < 2; ++nq) {
            float lt = lsum[nq] + red[qsub][32 + nq][lane];
            float inv_l = 1.0f / lt;
            int qg_global = q0 + nq * 16 + ln15;
            float* og = out + (bh * S_LEN + qg_global) * DHEAD;
#pragma unroll
            for (int vt = 0; vt < 4; ++vt) {
                float4_t vals;
#pragma unroll
                for (int r = 0; r < 4; ++r)
                    vals[r] = (o[nq][vt][r] + red[qsub][nq * 16 + vt * 4 + r][lane]) * inv_l;
                *(float4_t*)(og + vt * 16 + g * 4) = vals;
            }
        }
    }
}

// ---------------- launch ----------------

extern "C" void kernel_launch(void* const* d_in, const int* in_sizes, int n_in,
                              void* d_out, int out_size, void* d_ws, size_t ws_size,
                              hipStream_t stream) {
    const float* Kin = (const float*)d_in[0];
    const float* Qin = (const float*)d_in[1];
    const float* Vin = (const float*)d_in[2];
    float* out = (float*)d_out;

    _Float16* Kf = (_Float16*)d_ws;                 // 8 MB
    _Float16* Vf = Kf + TENS_ELEMS;                 // 8 MB

    prep_kernel<<<BHEADS * NTILES, 256, 0, stream>>>(Kin, Vin, Kf, Vf);
    attn_kernel<<<BHEADS * 32, 256, 0, stream>>>(Qin, Kf, Vf, out);
}

// Round 5
// 128.274 us; speedup vs baseline: 3.0651x; 1.0407x over previous
//
#include <hip/hip_runtime.h>

// B=2, H=16, S=2048, DK=DV=64; out flat = [B,H,S,DV] flat (raw reshape).
#define S_LEN 2048
#define DHEAD 64
#define BHEADS 32
#define NTILES 32                       // key tiles of 64
#define HEAD_ELEMS (S_LEN * DHEAD)
#define TENS_ELEMS (BHEADS * HEAD_ELEMS)
#define TILE_HALVES 4096                // 8 KB per (bh,tile) fragment block

typedef _Float16 half8_t __attribute__((ext_vector_type(8)));
typedef _Float16 half4_t __attribute__((ext_vector_type(4)));
typedef _Float16 half2_t __attribute__((ext_vector_type(2)));
typedef float float4_t __attribute__((ext_vector_type(4)));

// 1/sqrt(64) * log2(e), folded into K so scores land in exp2 domain
#define SC_LOG2E 0.18033688011112042f

// Fragment-linear layouts (16 B per lane per fragment):
//  Kf[bh][t][f=mt*2+kh][lane] : K[t*64 + mt*16 + (lane&15)][kh*32 + (lane>>4)*8 + j] * SC
//  Vf[bh][t][fv=vt*2+c][lane][j] : V[t*64 + c*32 + (j>>2)*16 + (lane>>4)*4 + (j&3)]
//                                   [vt*16 + (lane&15)]
// Key fact (R9): Vf's k-ordering equals the k-ordering of a P^T B-operand
// built by concatenating QK sub-tile outputs 2c (regs 0-3) and 2c+1 (regs
// 4-7), so PV can use mfma_f32_16x16x32_f16 directly — half the PV MFMAs.

// direct-to-LDS DMA: 64 lanes x 16 B, per-lane global src, linear LDS dest
typedef const __attribute__((address_space(1))) unsigned int gas_u32;
typedef __attribute__((address_space(3))) unsigned int las_u32;
__device__ __forceinline__ void stage16(const void* g, void* l) {
    __builtin_amdgcn_global_load_lds((gas_u32*)g, (las_u32*)l, 16, 0, 0);
}

// ---------------- prepass: build fragment-ordered K/VT ----------------
__global__ __launch_bounds__(256) void prep_kernel(const float* __restrict__ K,
                                                   const float* __restrict__ V,
                                                   _Float16* __restrict__ Kf,
                                                   _Float16* __restrict__ Vf) {
    __shared__ _Float16 tile[64][72];   // V tile [s][v], padded
    const int bh = blockIdx.x >> 5;
    const int t = blockIdx.x & 31;
    const int tid = threadIdx.x;

    const float* Ksrc = K + (bh * S_LEN + t * 64) * DHEAD;
    const float4* vs = (const float4*)(V + (bh * S_LEN + t * 64) * DHEAD);
#pragma unroll
    for (int it = 0; it < 4; ++it) {
        int i = it * 256 + tid;                 // 1024 float4 = 64x64 floats
        float4 vv = vs[i];
        int r = i >> 4, c4 = (i & 15) * 4;
        half4_t hv = {(_Float16)vv.x, (_Float16)vv.y, (_Float16)vv.z, (_Float16)vv.w};
        *(half4_t*)&tile[r][c4] = hv;
    }

    // K fragments: pure permutation of the fp32 tile, no LDS needed
    _Float16* kd = Kf + (bh * NTILES + t) * TILE_HALVES;
#pragma unroll
    for (int it = 0; it < 2; ++it) {
        int c = it * 256 + tid;                 // 512 chunks of 16 B
        int f = c >> 6, lane = c & 63;
        int row = (f >> 1) * 16 + (lane & 15);
        int d0 = (f & 1) * 32 + (lane >> 4) * 8;
        const float4* s = (const float4*)(Ksrc + row * DHEAD + d0);
        float4 a = s[0], b = s[1];
        half8_t h = {(_Float16)(a.x * SC_LOG2E), (_Float16)(a.y * SC_LOG2E),
                     (_Float16)(a.z * SC_LOG2E), (_Float16)(a.w * SC_LOG2E),
                     (_Float16)(b.x * SC_LOG2E), (_Float16)(b.y * SC_LOG2E),
                     (_Float16)(b.z * SC_LOG2E), (_Float16)(b.w * SC_LOG2E)};
        *(half8_t*)(kd + c * 8) = h;
    }
    __syncthreads();

    // VT fragments: transpose gather from LDS
    _Float16* vd = Vf + (bh * NTILES + t) * TILE_HALVES;
#pragma unroll
    for (int it = 0; it < 2; ++it) {
        int c = it * 256 + tid;
        int fv = c >> 6, lane = c & 63;
        int vt = fv >> 1, ktp = fv & 1;
        int v = vt * 16 + (lane & 15);
        int g = lane >> 4;
        half8_t h;
#pragma unroll
        for (int j = 0; j < 8; ++j) {
            int key = ktp * 32 + (j >> 2) * 16 + g * 4 + (j & 3);
            h[j] = tile[key][v];
        }
        *(half8_t*)(vd + c * 8) = h;
    }
}

// ---------------- attention: LDS-staged KV, split-K x2, nq=4 ----------------
// Block = 4 waves = 2 q-groups (64 q each) x 2 k-splits (16 tiles each) — the
// proven R0 shape (45.5 us). R13 post-mortem: 2x occupancy left VALUBusy flat
// and time +13% => stalls are CORRELATED across waves (shared per-CU global
// load-return path), and time scales with global KV traffic. R11: prefetch
// at same traffic = neutral. => Attack traffic, not occupancy.
// R14: the two qg waves with equal ks read IDENTICAL tiles. Stage each
// ks-stream's tile ONCE per block into LDS via global_load_lds (16B DMA, no
// RF transit), double-buffered; both qg waves consume via linear
// ds_read_b128 (conflict-free, 128 B/cy pipe). Global KV traffic halves
// (512->256 MB). LDS kv[2 ks][2 buf][K,V][4096 h] = 64 KB; combine scratch
// red[2][68][64] (34.8 KB) OVERLAID on kv (only live after the loop) =>
// still 2 blocks/CU. Schedule: minimal 2-phase — issue stage(t+1), ds_read+
// compute(t), __syncthreads (drain ~400cy << phase ~5kcy, amortized).
// Staging roles: wave(qg,ks): qg=0 stages K frags of its ks, qg=1 stages V.
// XCD swizzle (R8) and nq=4 + K=32 PV (R9) kept. launch_bounds(256,2): the
// nq=4 live set (~170 unified) must NOT be capped tighter (R10/R12 spills).

__global__ __launch_bounds__(256, 2) void attn_kernel(
    const float* __restrict__ Qf,
    const _Float16* __restrict__ Kf,
    const _Float16* __restrict__ Vf,
    float* __restrict__ out) {
    __shared__ __align__(16) char smem[65536];
    _Float16 (*kv)[2][2][TILE_HALVES] = (_Float16 (*)[2][2][TILE_HALVES])smem; // [ks][buf][K/V][4096]
    float (*red)[68][64] = (float (*)[68][64])smem;                            // epilogue overlay

    const int tid = threadIdx.x;
    const int wid = tid >> 6;
    const int lane = tid & 63;
    const int ln15 = lane & 15;
    const int g = lane >> 4;

    const int bh = blockIdx.x & 31;          // head-major: head h -> XCD h%8
    const int qidx = blockIdx.x >> 5;        // 16 q-blocks per head (128 q each)
    const int qg = wid >> 1;                 // q-group within block
    const int ks = wid & 1;                  // k-split half
    const int q0 = qidx * 128 + qg * 64;
    const int t0 = ks * 16;                  // this ks-stream's 16 key tiles

    // ---- Q fragments (B-operand of 16x16x32), direct global fp32 -> f16 ----
    const float* Qg = Qf + (bh * S_LEN + q0) * DHEAD;
    half8_t qf[4][2];
#pragma unroll
    for (int nq = 0; nq < 4; ++nq)
#pragma unroll
        for (int kh = 0; kh < 2; ++kh) {
            const float4* qs = (const float4*)(Qg + (nq * 16 + ln15) * DHEAD + kh * 32 + g * 8);
            float4 a = qs[0], b = qs[1];
            qf[nq][kh] = (half8_t){(_Float16)a.x, (_Float16)a.y, (_Float16)a.z, (_Float16)a.w,
                                   (_Float16)b.x, (_Float16)b.y, (_Float16)b.z, (_Float16)b.w};
        }

    const _Float16* kb = Kf + bh * (NTILES * TILE_HALVES) + t0 * TILE_HALVES;
    const _Float16* vb = Vf + bh * (NTILES * TILE_HALVES) + t0 * TILE_HALVES;
    const int lo = lane * 8;                  // lane offset in halves (16 B)

    // this wave's staging role: qg=0 -> K stream, qg=1 -> V stream (same ks)
    const _Float16* gstage = (qg == 0) ? kb : vb;

    float lsum[4] = {0.f, 0.f, 0.f, 0.f};
    float4_t o[4][4];
#pragma unroll
    for (int nq = 0; nq < 4; ++nq)
#pragma unroll
        for (int vt = 0; vt < 4; ++vt) o[nq][vt] = (float4_t){0.f, 0.f, 0.f, 0.f};

    // ---- prologue: stage tile 0 into buf 0 ----
    {
        _Float16* ld = &kv[ks][0][qg][0];
#pragma unroll
        for (int f = 0; f < 8; ++f)
            stage16(gstage + f * 512 + lo, ld + f * 512);
    }
    __syncthreads();

#pragma unroll 2
    for (int t = 0; t < 16; ++t) {
        const int buf = t & 1;

        // issue next tile's staging into the other buffer (DMA, in-flight
        // across this tile's compute; drained by the end-of-phase barrier)
        if (t < 15) {
            const _Float16* gs = gstage + (t + 1) * TILE_HALVES + lo;
            _Float16* ld = &kv[ks][buf ^ 1][qg][0];
#pragma unroll
            for (int f = 0; f < 8; ++f)
                stage16(gs + f * 512, ld + f * 512);
        }

        // ---- consume tile t from LDS (linear, conflict-free b128) ----
        const _Float16* kl = &kv[ks][buf][0][0];
        const _Float16* vl = &kv[ks][buf][1][0];
        half8_t kf[8], vf[8];
#pragma unroll
        for (int f = 0; f < 8; ++f) kf[f] = *(const half8_t*)(kl + f * 512 + lo);
#pragma unroll
        for (int f = 0; f < 8; ++f) vf[f] = *(const half8_t*)(vl + f * 512 + lo);

        // two 32-key chunks; QK -> exp2 -> PV (K=32) per chunk
#pragma unroll
        for (int c = 0; c < 2; ++c) {
            half8_t pb[4];
#pragma unroll
            for (int h = 0; h < 2; ++h) {
                const int mt = 2 * c + h;
                half8_t a0 = kf[mt * 2];
                half8_t a1 = kf[mt * 2 + 1];
#pragma unroll
                for (int nq = 0; nq < 4; ++nq) {
                    float4_t c0 = (float4_t){0.f, 0.f, 0.f, 0.f};
                    c0 = __builtin_amdgcn_mfma_f32_16x16x32_f16(a0, qf[nq][0], c0, 0, 0, 0);
                    c0 = __builtin_amdgcn_mfma_f32_16x16x32_f16(a1, qf[nq][1], c0, 0, 0, 0);
                    float p0 = __builtin_amdgcn_exp2f(c0[0]);
                    float p1 = __builtin_amdgcn_exp2f(c0[1]);
                    float p2 = __builtin_amdgcn_exp2f(c0[2]);
                    float p3 = __builtin_amdgcn_exp2f(c0[3]);
                    lsum[nq] += (p0 + p1) + (p2 + p3);
                    half2_t plo = __builtin_bit_cast(half2_t, __builtin_amdgcn_cvt_pkrtz(p0, p1));
                    half2_t phi = __builtin_bit_cast(half2_t, __builtin_amdgcn_cvt_pkrtz(p2, p3));
                    pb[nq][h * 4 + 0] = plo[0];
                    pb[nq][h * 4 + 1] = plo[1];
                    pb[nq][h * 4 + 2] = phi[0];
                    pb[nq][h * 4 + 3] = phi[1];
                }
            }
            // ---- O^T += V^T . P^T over this 32-key chunk (K=32 MFMA) ----
#pragma unroll
            for (int vt = 0; vt < 4; ++vt) {
                half8_t va = vf[vt * 2 + c];
#pragma unroll
                for (int nq = 0; nq < 4; ++nq)
                    o[nq][vt] = __builtin_amdgcn_mfma_f32_16x16x32_f16(va, pb[nq], o[nq][vt], 0, 0, 0);
            }
        }

        __syncthreads();   // tile t consumed by both qg waves; stage(t+1) drained
    }

    // ---- cross-lane l reduction (per wave, over its key half) ----
#pragma unroll
    for (int nq = 0; nq < 4; ++nq) {
        float l = lsum[nq];
        l += __shfl_xor(l, 16, 64);
        l += __shfl_xor(l, 32, 64);
        lsum[nq] = l;                       // replicated across g-groups
    }

    // ---- split-K combine via LDS overlay (all tile reads done: barrier above) ----
    if (ks == 1) {
#pragma unroll
        for (int nq = 0; nq < 4; ++nq)
#pragma unroll
            for (int vt = 0; vt < 4; ++vt)
#pragma unroll
                for (int r = 0; r < 4; ++r)
                    red[qg][nq * 16 + vt * 4 + r][lane] = o[nq][vt][r];
#pragma unroll
        for (int nq = 0; nq < 4; ++nq) red[qg][64 + nq][lane] = lsum[nq];
    }
    __syncthreads();
    if (ks == 0) {
#pragma unroll
        for (int nq = 0; nq < 4; ++nq) {
            float lt = lsum[nq] + red[qg][64 + nq][lane];
            float inv_l = 1.0f / lt;
            int qg_global = q0 + nq * 16 + ln15;
            float* og = out + (bh * S_LEN + qg_global) * DHEAD;
#pragma unroll
            for (int vt = 0; vt < 4; ++vt) {
                float4_t vals;
#pragma unroll
                for (int r = 0; r < 4; ++r)
                    vals[r] = (o[nq][vt][r] + red[qg][nq * 16 + vt * 4 + r][lane]) * inv_l;
                *(float4_t*)(og + vt * 16 + g * 4) = vals;
            }
        }
    }
}

// ---------------- launch ----------------

extern "C" void kernel_launch(void* const* d_in, const int* in_sizes, int n_in,
                              void* d_out, int out_size, void* d_ws, size_t ws_size,
                              hipStream_t stream) {
    const float* Kin = (const float*)d_in[0];
    const float* Qin = (const float*)d_in[1];
    const float* Vin = (const float*)d_in[2];
    float* out = (float*)d_out;

    _Float16* Kf = (_Float16*)d_ws;                 // 8 MB
    _Float16* Vf = Kf + TENS_ELEMS;                 // 8 MB

    prep_kernel<<<BHEADS * NTILES, 256, 0, stream>>>(Kin, Vin, Kf, Vf);
    attn_kernel<<<BHEADS * 16, 256, 0, stream>>>(Qin, Kf, Vf, out);
}

// Round 6
// 126.093 us; speedup vs baseline: 3.1182x; 1.0173x over previous
//
#include <hip/hip_runtime.h>

// B=2, H=16, S=2048, DK=DV=64; out flat = [B,H,S,DV] flat (raw reshape).
#define S_LEN 2048
#define DHEAD 64
#define BHEADS 32
#define NTILES 32                       // key tiles of 64
#define HEAD_ELEMS (S_LEN * DHEAD)
#define TENS_ELEMS (BHEADS * HEAD_ELEMS)
#define TILE_HALVES 4096                // 8 KB per (bh,tile) fragment block

typedef _Float16 half8_t __attribute__((ext_vector_type(8)));
typedef _Float16 half4_t __attribute__((ext_vector_type(4)));
typedef _Float16 half2_t __attribute__((ext_vector_type(2)));
typedef float float4_t __attribute__((ext_vector_type(4)));

// 1/sqrt(64) * log2(e), folded into K so scores land in exp2 domain
#define SC_LOG2E 0.18033688011112042f

// Fragment-linear layouts (16 B per lane per fragment):
//  Kf[bh][t][f=mt*2+kh][lane] : K[t*64 + mt*16 + (lane&15)][kh*32 + (lane>>4)*8 + j] * SC
//  Vf[bh][t][fv=vt*2+c][lane][j] : V[t*64 + c*32 + (j>>2)*16 + (lane>>4)*4 + (j&3)]
//                                   [vt*16 + (lane&15)]
// Key fact (R9): Vf's k-ordering equals the k-ordering of a P^T B-operand
// built by concatenating QK sub-tile outputs 2c (regs 0-3) and 2c+1 (regs
// 4-7), so PV can use mfma_f32_16x16x32_f16 directly — half the PV MFMAs.

// ---------------- prepass: build fragment-ordered K/VT ----------------
__global__ __launch_bounds__(256) void prep_kernel(const float* __restrict__ K,
                                                   const float* __restrict__ V,
                                                   _Float16* __restrict__ Kf,
                                                   _Float16* __restrict__ Vf) {
    __shared__ _Float16 tile[64][72];   // V tile [s][v], padded
    const int bh = blockIdx.x >> 5;
    const int t = blockIdx.x & 31;
    const int tid = threadIdx.x;

    const float* Ksrc = K + (bh * S_LEN + t * 64) * DHEAD;
    const float4* vs = (const float4*)(V + (bh * S_LEN + t * 64) * DHEAD);
#pragma unroll
    for (int it = 0; it < 4; ++it) {
        int i = it * 256 + tid;                 // 1024 float4 = 64x64 floats
        float4 vv = vs[i];
        int r = i >> 4, c4 = (i & 15) * 4;
        half4_t hv = {(_Float16)vv.x, (_Float16)vv.y, (_Float16)vv.z, (_Float16)vv.w};
        *(half4_t*)&tile[r][c4] = hv;
    }

    // K fragments: pure permutation of the fp32 tile, no LDS needed
    _Float16* kd = Kf + (bh * NTILES + t) * TILE_HALVES;
#pragma unroll
    for (int it = 0; it < 2; ++it) {
        int c = it * 256 + tid;                 // 512 chunks of 16 B
        int f = c >> 6, lane = c & 63;
        int row = (f >> 1) * 16 + (lane & 15);
        int d0 = (f & 1) * 32 + (lane >> 4) * 8;
        const float4* s = (const float4*)(Ksrc + row * DHEAD + d0);
        float4 a = s[0], b = s[1];
        half8_t h = {(_Float16)(a.x * SC_LOG2E), (_Float16)(a.y * SC_LOG2E),
                     (_Float16)(a.z * SC_LOG2E), (_Float16)(a.w * SC_LOG2E),
                     (_Float16)(b.x * SC_LOG2E), (_Float16)(b.y * SC_LOG2E),
                     (_Float16)(b.z * SC_LOG2E), (_Float16)(b.w * SC_LOG2E)};
        *(half8_t*)(kd + c * 8) = h;
    }
    __syncthreads();

    // VT fragments: transpose gather from LDS
    _Float16* vd = Vf + (bh * NTILES + t) * TILE_HALVES;
#pragma unroll
    for (int it = 0; it < 2; ++it) {
        int c = it * 256 + tid;
        int fv = c >> 6, lane = c & 63;
        int vt = fv >> 1, ktp = fv & 1;
        int v = vt * 16 + (lane & 15);
        int g = lane >> 4;
        half8_t h;
#pragma unroll
        for (int j = 0; j < 8; ++j) {
            int key = ktp * 32 + (j >> 2) * 16 + g * 4 + (j & 3);
            h[j] = tile[key][v];
        }
        *(half8_t*)(vd + c * 8) = h;
    }
}

// ---------------- attention: R0 structure + s_setprio de-phasing ----------------
// Block = 4 waves = 2 q-groups (64 queries each) x 2 k-splits (16 tiles each).
// Session ledger:
//  R10/R12: launch_bounds cap below ~170 unified regs (o[4][4]=64 AGPR!) =>
//           spill, 1.4 GB scratch. Never cap below (256,2) at nq=4.
//  R11: manual register pipeline = neutral (compiler already pipelines).
//  R13: 2x occupancy (nq=2) = neutral utilizations, +13% time from 2x traffic.
//  R14: LDS-staged KV (halved global traffic, DMA prefetch) = neutral.
//  => Memory side and occupancy are NOT binding. Per-tile wall ~6.8k cyc for
//  2 phase-locked waves: both run identical code against the shared load
//  return queue, so they want the same pipe at the same time and share the
//  same cross-pipe bubbles (MFMA->exp2 latency, pb->PV wait).
// R15: de-phase via s_setprio (T5): boost MFMA clusters so the wave entering
// its MFMA phase preempts the other wave's issue, forcing anti-phase drift
// (barrier-free loop = waves are free to drift). QK pair + PV cluster wrapped.
// XCD swizzle (R8): head = blockIdx % 32 => KV L2-resident per XCD.
// nq=4 + K=32 PV (R9): double independent MFMA chains, halve PV MFMA count.

__global__ __launch_bounds__(256, 2) void attn_kernel(
    const float* __restrict__ Qf,
    const _Float16* __restrict__ Kf,
    const _Float16* __restrict__ Vf,
    float* __restrict__ out) {
    __shared__ float red[2][68][64];    // [qg][64 o-floats + 4 lsum][lane]

    const int tid = threadIdx.x;
    const int wid = tid >> 6;
    const int lane = tid & 63;
    const int ln15 = lane & 15;
    const int g = lane >> 4;

    const int bh = blockIdx.x & 31;          // head-major: head h -> XCD h%8
    const int qidx = blockIdx.x >> 5;        // 16 q-blocks per head (128 q each)
    const int qg = wid >> 1;                 // q-group within block
    const int ks = wid & 1;                  // k-split half
    const int q0 = qidx * 128 + qg * 64;
    const int t0 = ks * 16;                  // this wave's 16 key tiles

    // ---- Q fragments (B-operand of 16x16x32), direct global fp32 -> f16 ----
    const float* Qg = Qf + (bh * S_LEN + q0) * DHEAD;
    half8_t qf[4][2];
#pragma unroll
    for (int nq = 0; nq < 4; ++nq)
#pragma unroll
        for (int kh = 0; kh < 2; ++kh) {
            const float4* qs = (const float4*)(Qg + (nq * 16 + ln15) * DHEAD + kh * 32 + g * 8);
            float4 a = qs[0], b = qs[1];
            qf[nq][kh] = (half8_t){(_Float16)a.x, (_Float16)a.y, (_Float16)a.z, (_Float16)a.w,
                                   (_Float16)b.x, (_Float16)b.y, (_Float16)b.z, (_Float16)b.w};
        }

    const _Float16* kb = Kf + bh * (NTILES * TILE_HALVES) + t0 * TILE_HALVES;
    const _Float16* vb = Vf + bh * (NTILES * TILE_HALVES) + t0 * TILE_HALVES;
    const int lo = lane * 8;                  // lane offset in halves

    float lsum[4] = {0.f, 0.f, 0.f, 0.f};
    float4_t o[4][4];
#pragma unroll
    for (int nq = 0; nq < 4; ++nq)
#pragma unroll
        for (int vt = 0; vt < 4; ++vt) o[nq][vt] = (float4_t){0.f, 0.f, 0.f, 0.f};

#pragma unroll 2
    for (int t = 0; t < 16; ++t) {
        const int base = t * TILE_HALVES;
        half8_t kf[8], vf[8];
#pragma unroll
        for (int f = 0; f < 8; ++f) kf[f] = *(const half8_t*)(kb + base + f * 512 + lo);
#pragma unroll
        for (int f = 0; f < 8; ++f) vf[f] = *(const half8_t*)(vb + base + f * 512 + lo);

        // two 32-key chunks; QK -> exp2 -> PV (K=32) per chunk
#pragma unroll
        for (int c = 0; c < 2; ++c) {
            half8_t pb[4];
#pragma unroll
            for (int h = 0; h < 2; ++h) {
                const int mt = 2 * c + h;
                half8_t a0 = kf[mt * 2];
                half8_t a1 = kf[mt * 2 + 1];
#pragma unroll
                for (int nq = 0; nq < 4; ++nq) {
                    float4_t c0 = (float4_t){0.f, 0.f, 0.f, 0.f};
                    __builtin_amdgcn_s_setprio(1);      // T5: MFMA wave wins issue
                    c0 = __builtin_amdgcn_mfma_f32_16x16x32_f16(a0, qf[nq][0], c0, 0, 0, 0);
                    c0 = __builtin_amdgcn_mfma_f32_16x16x32_f16(a1, qf[nq][1], c0, 0, 0, 0);
                    __builtin_amdgcn_s_setprio(0);
                    float p0 = __builtin_amdgcn_exp2f(c0[0]);
                    float p1 = __builtin_amdgcn_exp2f(c0[1]);
                    float p2 = __builtin_amdgcn_exp2f(c0[2]);
                    float p3 = __builtin_amdgcn_exp2f(c0[3]);
                    lsum[nq] += (p0 + p1) + (p2 + p3);
                    half2_t plo = __builtin_bit_cast(half2_t, __builtin_amdgcn_cvt_pkrtz(p0, p1));
                    half2_t phi = __builtin_bit_cast(half2_t, __builtin_amdgcn_cvt_pkrtz(p2, p3));
                    pb[nq][h * 4 + 0] = plo[0];
                    pb[nq][h * 4 + 1] = plo[1];
                    pb[nq][h * 4 + 2] = phi[0];
                    pb[nq][h * 4 + 3] = phi[1];
                }
            }
            // ---- O^T += V^T . P^T over this 32-key chunk (K=32 MFMA) ----
            __builtin_amdgcn_s_setprio(1);              // T5: pure-MFMA cluster
#pragma unroll
            for (int vt = 0; vt < 4; ++vt) {
                half8_t va = vf[vt * 2 + c];
#pragma unroll
                for (int nq = 0; nq < 4; ++nq)
                    o[nq][vt] = __builtin_amdgcn_mfma_f32_16x16x32_f16(va, pb[nq], o[nq][vt], 0, 0, 0);
            }
            __builtin_amdgcn_s_setprio(0);
        }
    }

    // ---- cross-lane l reduction (per wave, over its key half) ----
#pragma unroll
    for (int nq = 0; nq < 4; ++nq) {
        float l = lsum[nq];
        l += __shfl_xor(l, 16, 64);
        l += __shfl_xor(l, 32, 64);
        lsum[nq] = l;                       // replicated across g-groups
    }

    // ---- split-K combine via LDS (conflict-free column layout) ----
    if (ks == 1) {
#pragma unroll
        for (int nq = 0; nq < 4; ++nq)
#pragma unroll
            for (int vt = 0; vt < 4; ++vt)
#pragma unroll
                for (int r = 0; r < 4; ++r)
                    red[qg][nq * 16 + vt * 4 + r][lane] = o[nq][vt][r];
#pragma unroll
        for (int nq = 0; nq < 4; ++nq) red[qg][64 + nq][lane] = lsum[nq];
    }
    __syncthreads();
    if (ks == 0) {
#pragma unroll
        for (int nq = 0; nq < 4; ++nq) {
            float lt = lsum[nq] + red[qg][64 + nq][lane];
            float inv_l = 1.0f / lt;
            int qg_global = q0 + nq * 16 + ln15;
            float* og = out + (bh * S_LEN + qg_global) * DHEAD;
#pragma unroll
            for (int vt = 0; vt < 4; ++vt) {
                float4_t vals;
#pragma unroll
                for (int r = 0; r < 4; ++r)
                    vals[r] = (o[nq][vt][r] + red[qg][nq * 16 + vt * 4 + r][lane]) * inv_l;
                *(float4_t*)(og + vt * 16 + g * 4) = vals;
            }
        }
    }
}

// ---------------- launch ----------------

extern "C" void kernel_launch(void* const* d_in, const int* in_sizes, int n_in,
                              void* d_out, int out_size, void* d_ws, size_t ws_size,
                              hipStream_t stream) {
    const float* Kin = (const float*)d_in[0];
    const float* Qin = (const float*)d_in[1];
    const float* Vin = (const float*)d_in[2];
    float* out = (float*)d_out;

    _Float16* Kf = (_Float16*)d_ws;                 // 8 MB
    _Float16* Vf = Kf + TENS_ELEMS;                 // 8 MB

    prep_kernel<<<BHEADS * NTILES, 256, 0, stream>>>(Kin, Vin, Kf, Vf);
    attn_kernel<<<BHEADS * 16, 256, 0, stream>>>(Qin, Kf, Vf, out);
}